// Round 3
// baseline (583.303 us; speedup 1.0000x reference)
//
#include <hip/hip_runtime.h>

// TTFS encoder: out[b][t][n] = 1.0f at the first t where the leaky-integrate
// membrane crosses V_TH=1.0, else 0.0f. Output is one-hot (or all-zero) per
// (b,n) column across t: with x~N(0,1) only ~16% of columns ever fire
// (~330K ones in a 134M-element output).
//
// R5 post-mortem: hipMemsetAsync inside kernel_launch -> "container failed
// twice". The harness graph-captures kernel_launch; the rocclr fill dispatched
// by hipMemsetAsync is evidently not capture-safe here. Rule reaffirmed: only
// plain kernel launches (+hipMemcpyAsync) inside kernel_launch.
//
// R6: same sparse plan, but the zero-fill is OUR OWN kernel:
//   1) ttfs_zero_kernel: pure grid-stride float4 stores, no cross-iteration
//      deps -- structurally identical to rocclr fillBufferAligned (which
//      sustains 6.3 TB/s on this buffer). Zeros are bit-exact 0.0f.
//   2) ttfs_scatter_kernel: bit-exact recurrence in registers (unchanged:
//      __fmul_rn/__fadd_rn order, reset-on-every-spike, first-spike-only),
//      then <=4 scattered 4B stores per thread writing only the 1.0f elems.
// Diagnostic value: our fill kernel appears in rocprof with its own dur_us &
// WRITE_SIZE=524288 KB -> directly measures what plain-HIP dense stores do on
// this buffer (World A: ~170us/3TB/s vs World B: ~85us/6.3TB/s).
// Decision rule: dur_us ~450 => win, keep. dur_us flat => decompose from the
// new per-kernel rocprof rows and conclude.
//
// Bit-exactness notes (output is {0,1}: one flipped element = absmax 1.0):
//  - decay = fp32(exp(-0.5)) correctly rounded; (1-decay) exact (Sterbenz).
//  - mem update is mul-then-add round-to-nearest, NOT fma (__fmul_rn/__fadd_rn
//    block -ffp-contract=fast).
//  - drive = (x*s)*(1-decay) precomputed once: deterministic, same rounding
//    as reference's per-step current*(1-decay).

#define T_STEPS 64
#define N_COLS  1024

typedef float vfloat4 __attribute__((ext_vector_type(4)));

__global__ __launch_bounds__(256) void ttfs_zero_kernel(
    vfloat4* __restrict__ out4, unsigned int n4)
{
    const vfloat4 z = {0.f, 0.f, 0.f, 0.f};
    const unsigned int stride = gridDim.x * 256u;
    // 33,554,432 float4s / (2048*256 threads) = 64 stores/thread.
    for (unsigned int i = blockIdx.x * 256u + threadIdx.x; i < n4; i += stride)
        out4[i] = z;
}

__global__ __launch_bounds__(256) void ttfs_scatter_kernel(
    const float* __restrict__ x,
    const float* __restrict__ sens,
    float* __restrict__ out)
{
    const int b   = blockIdx.x;
    const int tid = threadIdx.x;      // 0..255, each owns 4 consecutive cols
    const int n0  = tid * 4;

    const float decay = 0.60653065971263342f;  // fp32(exp(-0.5)), CR
    const float omd   = 1.0f - decay;          // exact (Sterbenz)

    const vfloat4 xv = *reinterpret_cast<const vfloat4*>(x + (size_t)b * N_COLS + n0);
    const vfloat4 sv = *reinterpret_cast<const vfloat4*>(sens + n0);

    // drive_i = (x*s)*(1-decay): two rn muls, matching reference op order.
    float drive[4];
    #pragma unroll
    for (int i = 0; i < 4; ++i)
        drive[i] = __fmul_rn(__fmul_rn(xv[i], sv[i]), omd);

    // Exact recurrence in registers; record first-spike step per column.
    int   tstar[4] = {T_STEPS, T_STEPS, T_STEPS, T_STEPS};  // T_STEPS = never
    float mem[4]   = {0.f, 0.f, 0.f, 0.f};

    #pragma unroll 8
    for (int t = 0; t < T_STEPS; ++t) {
        #pragma unroll
        for (int i = 0; i < 4; ++i) {
            float m = __fadd_rn(__fmul_rn(mem[i], decay), drive[i]);
            const bool spike = (m >= 1.0f);
            if (spike && tstar[i] == T_STEPS) tstar[i] = t;  // first spike only
            mem[i] = spike ? 0.0f : m;
        }
    }

    // Scatter only the ones; zeros were produced by the fill kernel.
    float* rowb = out + (size_t)b * T_STEPS * N_COLS + n0;
    #pragma unroll
    for (int i = 0; i < 4; ++i) {
        if (tstar[i] < T_STEPS)
            rowb[(size_t)tstar[i] * N_COLS + i] = 1.0f;
    }
}

extern "C" void kernel_launch(void* const* d_in, const int* in_sizes, int n_in,
                              void* d_out, int out_size, void* d_ws, size_t ws_size,
                              hipStream_t stream) {
    const float* x    = (const float*)d_in[0];   // [B, N] fp32
    const float* sens = (const float*)d_in[1];   // [N]    fp32
    float*       out  = (float*)d_out;           // [B, T, N] fp32

    const int N = in_sizes[1];                   // 1024
    const int B = in_sizes[0] / N;               // 2048
    (void)N; (void)out_size; (void)d_ws; (void)ws_size; (void)n_in;

    const unsigned int n4 = (unsigned int)((size_t)B * T_STEPS * N_COLS / 4);

    // Phase 1: zero the output (same-stream ordering guarantees completion
    // before the scatter kernel runs).
    ttfs_zero_kernel<<<dim3(2048), dim3(256), 0, stream>>>(
        reinterpret_cast<vfloat4*>(out), n4);

    // Phase 2: compute first-spike times and scatter the ones.
    ttfs_scatter_kernel<<<dim3(B), dim3(256), 0, stream>>>(x, sens, out);
}

// Round 4
// 526.679 us; speedup vs baseline: 1.1075x; 1.1075x over previous
//
#include <hip/hip_runtime.h>

// TTFS encoder: out[b][t][n] = 1.0f at the first t where the leaky-integrate
// membrane crosses V_TH=1.0, else 0.0f. One-hot (or zero) per (b,n) column.
//
// R6 post-mortem: split fill+scatter = 583us (+61 vs R4's 522). Our own pure
// float4 fill kernel is gated the same (~3 TB/s) as every other store pattern
// we've emitted (nt/plain/interleaved/decoupled all identical). The rocclr
// 2 GiB arena poison in the SAME timed window sustains 6.24 TB/s. Its one
// visible structural difference: OccupancyPercent ~10 (~800 waves, ~3/CU)
// vs our 8192 waves (100%).
// R7 theory: 8192 concurrent 1 KiB store streams thrash HBM row buffers
// (dozens of open-row competitors per channel -> ~2x efficiency loss); a few
// hundred streams keep row locality. AMD's blit fills are deliberately small-
// grid. Single-variable change vs R4: same kernel body, launched as a
// 512-block grid-stride over b (2 blocks/CU, 25% occupancy, 4 b's per block).
// Predict: our portion 177 -> ~95-110us, dur_us 522 -> ~440-460. If flat:
// occupancy theory dead; next discriminator = inline-asm buffer_store flags.
//
// Bit-exactness notes (output is {0,1}: one flipped element = absmax 1.0):
//  - decay = fp32(exp(-0.5)) correctly rounded; (1-decay) exact (Sterbenz).
//  - mem update is mul-then-add round-to-nearest, NOT fma (__fmul_rn/__fadd_rn
//    block -ffp-contract=fast).
//  - drive = (x*s)*(1-decay) precomputed once: deterministic, same rounding
//    as reference's per-step current*(1-decay).

#define T_STEPS 64
#define N_COLS  1024

typedef float vfloat4 __attribute__((ext_vector_type(4)));

__global__ __launch_bounds__(256) void ttfs_encode_kernel(
    const float* __restrict__ x,
    const float* __restrict__ sens,
    float* __restrict__ out,
    int B)
{
    const int tid = threadIdx.x;      // 0..255, each owns 4 consecutive cols
    const int n0  = tid * 4;

    const float decay = 0.60653065971263342f;  // fp32(exp(-0.5)), CR
    const float omd   = 1.0f - decay;          // exact (Sterbenz)

    // sens is b-invariant: load once.
    const vfloat4 sv = *reinterpret_cast<const vfloat4*>(sens + n0);

    for (int b = blockIdx.x; b < B; b += gridDim.x) {
        const vfloat4 xv =
            *reinterpret_cast<const vfloat4*>(x + (size_t)b * N_COLS + n0);

        // drive_i = (x*s)*(1-decay): two rn muls, matching reference order.
        float drive[4];
        #pragma unroll
        for (int i = 0; i < 4; ++i)
            drive[i] = __fmul_rn(__fmul_rn(xv[i], sv[i]), omd);

        // Phase 1: exact recurrence in registers; record first-spike step.
        int   tstar[4] = {T_STEPS, T_STEPS, T_STEPS, T_STEPS};
        float mem[4]   = {0.f, 0.f, 0.f, 0.f};

        #pragma unroll 8
        for (int t = 0; t < T_STEPS; ++t) {
            #pragma unroll
            for (int i = 0; i < 4; ++i) {
                float m = __fadd_rn(__fmul_rn(mem[i], decay), drive[i]);
                const bool spike = (m >= 1.0f);
                if (spike && tstar[i] == T_STEPS) tstar[i] = t;
                mem[i] = spike ? 0.0f : m;
            }
        }

        // Phase 2: dense one-hot store sweep (independent iterations,
        // full-line coalesced 1 KiB/wave, write-once).
        float* outp = out + (size_t)b * T_STEPS * N_COLS + n0;
        #pragma unroll 8
        for (int t = 0; t < T_STEPS; ++t) {
            vfloat4 ov;
            #pragma unroll
            for (int i = 0; i < 4; ++i)
                ov[i] = (t == tstar[i]) ? 1.0f : 0.0f;
            *reinterpret_cast<vfloat4*>(outp) = ov;
            outp += N_COLS;
        }
    }
}

extern "C" void kernel_launch(void* const* d_in, const int* in_sizes, int n_in,
                              void* d_out, int out_size, void* d_ws, size_t ws_size,
                              hipStream_t stream) {
    const float* x    = (const float*)d_in[0];   // [B, N] fp32
    const float* sens = (const float*)d_in[1];   // [N]    fp32
    float*       out  = (float*)d_out;           // [B, T, N] fp32

    const int N = in_sizes[1];                   // 1024
    const int B = in_sizes[0] / N;               // 2048
    (void)N; (void)out_size; (void)d_ws; (void)ws_size; (void)n_in;

    // 512 blocks = 2 blocks/CU = 8 waves/CU (25% occupancy): few store
    // streams -> HBM row-buffer locality (the fill kernel's regime).
    ttfs_encode_kernel<<<dim3(512), dim3(256), 0, stream>>>(x, sens, out, B);
}